// Round 1
// baseline (2010.573 us; speedup 1.0000x reference)
//
#include <hip/hip_runtime.h>
#include <math.h>

// PosteriorRotationLayer: B=1, T=2048, D=1024, H=16, d=64, Tc=2016
//  kvfull = context @ Wkv + bkv            (kernel gemm_kv)
//  kvn    = LN_d64(split(kvfull))          (kernel ln_kv)   layout [h][s][d]
//  per (h,t): q = xh@Wq+bq; sk_s = tanh(q . kvn[h][s]);
//  out[j] = xh[j] + eps*( sum_{i<j} sk[p(j,i)]*xh[i] - sum_{i>j} sk[p(i,j)]*xh[i] )
//  p(j,i) = j*(j-1)/2 + i  (tril_indices(d,-1) row-major)

#define NT 2048
#define ND 1024
#define NH 16
#define DH 64
#define TC 2016
#define EPS_ROT 0.01f
#define LN_EPS 1e-5f
#define SC 512   // s-chunk in rot_kernel

__device__ inline float tanh_fast(float x) {
    float c = fminf(fmaxf(x, -15.f), 15.f);   // tanh(15)==1.0f in f32; avoids exp overflow
    float e = __expf(2.f * c);
#if __has_builtin(__builtin_amdgcn_rcpf)
    return (e - 1.f) * __builtin_amdgcn_rcpf(e + 1.f);
#else
    return (e - 1.f) / (e + 1.f);
#endif
}

// ---------------- kernel A1: kvfull[s][n] = context[s][:] @ Wkv[:][n] + bkv[n]
// M=2016, N=1024, K=1024. BM=64, BN=128, BK=16, 128 threads, 8x8 thread tile.
__global__ __launch_bounds__(128) void gemm_kv(const float* __restrict__ ctx,
                                               const float* __restrict__ Wkv,
                                               const float* __restrict__ bkv,
                                               float* __restrict__ kvfull) {
    __shared__ float as[16][64];    // A-tile transposed: as[k][row]
    __shared__ float bs[16][128];   // bs[k][col]
    const int tid = threadIdx.x;
    const int m0 = blockIdx.y * 64;
    const int n0 = blockIdx.x * 128;
    const int ty = tid >> 4;   // 0..7  -> rows ty*8..+7
    const int tx = tid & 15;   // 0..15 -> cols tx*8..+7
    float acc[8][8];
#pragma unroll
    for (int r = 0; r < 8; ++r)
#pragma unroll
        for (int c = 0; c < 8; ++c) acc[r][c] = 0.f;

    for (int k0 = 0; k0 < ND; k0 += 16) {
#pragma unroll
        for (int it = 0; it < 2; ++it) {           // A: 64x16 transposed
            int idx = tid + it * 128;
            int row = idx >> 2, k4 = idx & 3;
            int grow = m0 + row; if (grow > TC - 1) grow = TC - 1;  // clamp tail reads
            const float4 v = *(const float4*)&ctx[(size_t)grow * ND + k0 + k4 * 4];
            as[k4 * 4 + 0][row] = v.x; as[k4 * 4 + 1][row] = v.y;
            as[k4 * 4 + 2][row] = v.z; as[k4 * 4 + 3][row] = v.w;
        }
#pragma unroll
        for (int it = 0; it < 4; ++it) {           // B: 16x128
            int idx = tid + it * 128;
            int row = idx >> 5, col4 = idx & 31;
            *(float4*)&bs[row][col4 * 4] =
                *(const float4*)&Wkv[(size_t)(k0 + row) * ND + n0 + col4 * 4];
        }
        __syncthreads();
#pragma unroll
        for (int k = 0; k < 16; ++k) {
            float a[8], b[8];
            *(float4*)&a[0] = *(const float4*)&as[k][ty * 8];
            *(float4*)&a[4] = *(const float4*)&as[k][ty * 8 + 4];
            *(float4*)&b[0] = *(const float4*)&bs[k][tx * 8];
            *(float4*)&b[4] = *(const float4*)&bs[k][tx * 8 + 4];
#pragma unroll
            for (int r = 0; r < 8; ++r)
#pragma unroll
                for (int c = 0; c < 8; ++c) acc[r][c] += a[r] * b[c];
        }
        __syncthreads();
    }
#pragma unroll
    for (int r = 0; r < 8; ++r) {
        int row = m0 + ty * 8 + r;
        if (row < TC) {
#pragma unroll
            for (int c2 = 0; c2 < 2; ++c2) {
                int col = n0 + tx * 8 + c2 * 4;
                float4 v;
                v.x = acc[r][c2 * 4 + 0] + bkv[col + 0];
                v.y = acc[r][c2 * 4 + 1] + bkv[col + 1];
                v.z = acc[r][c2 * 4 + 2] + bkv[col + 2];
                v.w = acc[r][c2 * 4 + 3] + bkv[col + 3];
                *(float4*)&kvfull[(size_t)row * ND + col] = v;
            }
        }
    }
}

// ---------------- kernel A2: layernorm over d=64 chunks (torch-style: ddof=1, /(std+eps))
// kvn[h][s][j] = gamma[j]*(v-mean)/(std+eps)+beta[j],  v = kvfull[s][h*64+j]
__global__ __launch_bounds__(256) void ln_kv(const float* __restrict__ kvfull,
                                             const float* __restrict__ gamma,
                                             const float* __restrict__ beta,
                                             float* __restrict__ kvn) {
    int u = blockIdx.x * 4 + (threadIdx.x >> 6);   // unit = (s,h)
    int j = threadIdx.x & 63;
    int s = u >> 4;
    int h = u & 15;
    float v = kvfull[(size_t)s * ND + h * DH + j];
    float sum = v;
#pragma unroll
    for (int off = 32; off > 0; off >>= 1) sum += __shfl_xor(sum, off, 64);
    float mean = sum * (1.f / 64.f);
    float diff = v - mean;
    float sq = diff * diff;
#pragma unroll
    for (int off = 32; off > 0; off >>= 1) sq += __shfl_xor(sq, off, 64);
    float stdv = sqrtf(sq * (1.f / 63.f));         // unbiased (ddof=1)
    float o = gamma[j] * diff / (stdv + LN_EPS) + beta[j];
    kvn[((size_t)h * TC + s) * DH + j] = o;
}

// ---------------- kernel B: fused q-proj + skew + rotation
// grid (T/16, H), 256 threads. LDS: xs[16][68], qs[16][68], sk[16][516] = 41.7KB -> 3 blk/CU
__global__ __launch_bounds__(256) void rot_kernel(const float* __restrict__ x,
                                                  const float* __restrict__ Wq,
                                                  const float* __restrict__ bq,
                                                  const float* __restrict__ kvn,
                                                  float* __restrict__ out) {
    __shared__ float xs[16][68];   // pad 68: t-groups land on distinct banks, 16B aligned
    __shared__ float qs[16][68];
    __shared__ float sk[16][516];  // 516 pad: same reason
    const int tid = threadIdx.x;
    const int h = blockIdx.y;
    const int t0 = blockIdx.x * 16;

    {   // stage xh tile: 16 tokens x 64 dims
        int r = tid >> 4, c4 = tid & 15;
        *(float4*)&xs[r][c4 * 4] =
            *(const float4*)&x[(size_t)(t0 + r) * ND + h * DH + c4 * 4];
    }
    __syncthreads();
    {   // q[t][j] = bq[j] + sum_i xs[t][i]*Wq[i][j]   (thread = (t, j4), 4 j's each)
        int t = tid >> 4, j4 = tid & 15;
        float4 b4 = *(const float4*)&bq[j4 * 4];
        float a0 = b4.x, a1 = b4.y, a2 = b4.z, a3 = b4.w;
        for (int i = 0; i < 64; ++i) {
            float xv = xs[t][i];
            const float4 w = *(const float4*)&Wq[i * DH + j4 * 4];
            a0 += xv * w.x; a1 += xv * w.y; a2 += xv * w.z; a3 += xv * w.w;
        }
        qs[t][j4 * 4 + 0] = a0; qs[t][j4 * 4 + 1] = a1;
        qs[t][j4 * 4 + 2] = a2; qs[t][j4 * 4 + 3] = a3;
    }
    __syncthreads();

    const int w = tid >> 6;          // wave id 0..3
    const int j = tid & 63;          // output dim owned in phase 2
    const int jb = j * (j - 1) / 2;  // tril row base p(j,0)
    float xracc[4] = {0.f, 0.f, 0.f, 0.f};
    const float* kvh = kvn + (size_t)h * TC * DH;

    for (int s0 = 0; s0 < TC; s0 += SC) {
        const int s1 = (s0 + SC < TC) ? (s0 + SC) : TC;
        // ---- phase 1: sk[t][s-s0] = tanh(q[t] . kvn[h][s]),  thread=(t,sl), 4 s per iter
        {
            int t = tid >> 4, sl = tid & 15;
            for (int it = 0; it < SC / 64; ++it) {
                int sb = s0 + it * 64 + sl * 4;
                if (sb < s1) {
                    float a0 = 0.f, a1 = 0.f, a2 = 0.f, a3 = 0.f;
                    const float* p0 = kvh + (size_t)(sb + 0) * DH;
                    const float* p1 = kvh + (size_t)(sb + 1) * DH;
                    const float* p2 = kvh + (size_t)(sb + 2) * DH;
                    const float* p3 = kvh + (size_t)(sb + 3) * DH;
#pragma unroll
                    for (int i4 = 0; i4 < 16; ++i4) {
                        const float4 q4 = *(const float4*)&qs[t][i4 * 4];
                        const float4 k0 = *(const float4*)&p0[i4 * 4];
                        const float4 k1 = *(const float4*)&p1[i4 * 4];
                        const float4 k2 = *(const float4*)&p2[i4 * 4];
                        const float4 k3 = *(const float4*)&p3[i4 * 4];
                        a0 += q4.x * k0.x + q4.y * k0.y + q4.z * k0.z + q4.w * k0.w;
                        a1 += q4.x * k1.x + q4.y * k1.y + q4.z * k1.z + q4.w * k1.w;
                        a2 += q4.x * k2.x + q4.y * k2.y + q4.z * k2.z + q4.w * k2.w;
                        a3 += q4.x * k3.x + q4.y * k3.y + q4.z * k3.z + q4.w * k3.w;
                    }
                    int o = sb - s0;
                    sk[t][o + 0] = tanh_fast(a0);
                    sk[t][o + 1] = tanh_fast(a1);
                    sk[t][o + 2] = tanh_fast(a2);
                    sk[t][o + 3] = tanh_fast(a3);
                }
            }
        }
        __syncthreads();
        // ---- phase 2: accumulate rotation, lane = j, waves split 16 t's
#pragma unroll
        for (int ti = 0; ti < 4; ++ti) {
            const int t = w + ti * 4;
            float acc = 0.f;
            // i<j: s = jb + i, consecutive — direct bounds
            int ilo = s0 - jb; if (ilo < 0) ilo = 0;
            int ihi = s1 - jb; if (ihi > j) ihi = j;
            for (int i = ilo; i < ihi; ++i)
                acc += sk[t][jb + i - s0] * xs[t][i];
            // i>j: s = i*(i-1)/2 + j, find smallest i with s>=s0 via sqrt + fixup
            int r = s0 - j;
            int i2;
            if (r <= ((j + 1) * j) / 2) {
                i2 = j + 1;
            } else {
                i2 = (int)((1.f + sqrtf(1.f + 8.f * (float)r)) * 0.5f);
                while (i2 * (i2 - 1) / 2 < r) ++i2;
                while (i2 > j + 1 && (i2 - 1) * (i2 - 2) / 2 >= r) --i2;
            }
            if (i2 < j + 1) i2 = j + 1;
            int s = i2 * (i2 - 1) / 2 + j;
            for (int i = i2; i < 64 && s < s1; ++i) {
                acc -= sk[t][s - s0] * xs[t][i];
                s += i;   // s(i+1) = s(i) + i
            }
            xracc[ti] += acc;
        }
        __syncthreads();   // before next chunk overwrites sk
    }
#pragma unroll
    for (int ti = 0; ti < 4; ++ti) {
        const int t = w + ti * 4;
        out[(size_t)(t0 + t) * ND + h * DH + j] = xs[t][j] + EPS_ROT * xracc[ti];
    }
}

extern "C" void kernel_launch(void* const* d_in, const int* in_sizes, int n_in,
                              void* d_out, int out_size, void* d_ws, size_t ws_size,
                              hipStream_t stream) {
    const float* x     = (const float*)d_in[0];
    const float* ctx   = (const float*)d_in[1];
    const float* Wq    = (const float*)d_in[2];
    const float* bq    = (const float*)d_in[3];
    const float* Wkv   = (const float*)d_in[4];
    const float* bkv   = (const float*)d_in[5];
    const float* gamma = (const float*)d_in[6];
    const float* beta  = (const float*)d_in[7];
    float* outp = (float*)d_out;

    float* kvfull = (float*)d_ws;                      // 2016*1024 f32 = 8.25 MB
    float* kvn    = kvfull + (size_t)TC * ND;          // 16*2016*64 f32 = 8.25 MB

    gemm_kv<<<dim3(8, 32), 128, 0, stream>>>(ctx, Wkv, bkv, kvfull);
    ln_kv<<<dim3((TC * NH) / 4), 256, 0, stream>>>(kvfull, gamma, beta, kvn);
    rot_kernel<<<dim3(NT / 16, NH), 256, 0, stream>>>(x, Wq, bq, kvn, outp);
}

// Round 3
// 385.561 us; speedup vs baseline: 5.2147x; 5.2147x over previous
//
#include <hip/hip_runtime.h>
#include <math.h>

// PosteriorRotationLayer: B=1, T=2048, D=1024, H=16, d=64, Tc=2016
// Pipeline:
//   gemm_ln : kvn[h][s][d] = LN_d64(context @ Wkv + bkv)     (LN fused in epilogue)
//   skq     : sk[h][t][s]  = bf16(tanh(q_t . kvn[h][s])), q = xh@Wq+bq  (kv staged in LDS)
//   rot2    : out = x + eps * (A - A^T) x   via uniform 63-iter gather per (h,t,j)
// p(j,i) = j*(j-1)/2 + i  (tril_indices(d,-1) row-major)

#define NT 2048
#define ND 1024
#define NH 16
#define DH 64
#define TC 2016
#define EPS_ROT 0.01f
#define LN_EPS 1e-5f

__device__ inline float tanh_fast(float x) {
    float c = fminf(fmaxf(x, -15.f), 15.f);   // tanh(15)==1.0f in f32
    float e = __expf(2.f * c);
    return (e - 1.f) * __builtin_amdgcn_rcpf(e + 1.f);
}

__device__ inline unsigned short f32_to_bf16(float f) {  // RNE
    unsigned int b = __float_as_uint(f);
    unsigned int r = (b + 0x7FFFu + ((b >> 16) & 1u)) >> 16;
    return (unsigned short)r;
}

// ---------------- kernel 1: fused GEMM + LayerNorm -> kvn[h][s][d]
// M=2016(pad 2048), N=1024, K=1024. 64x64 tile, 256 thr, 4x4/thread.
// Each 64-col tile == one head's LN group; rows live in 16-lane subgroups.
__global__ __launch_bounds__(256) void gemm_ln(const float* __restrict__ ctx,
                                               const float* __restrict__ Wkv,
                                               const float* __restrict__ bkv,
                                               const float* __restrict__ gamma,
                                               const float* __restrict__ beta,
                                               float* __restrict__ kvn) {
    __shared__ float asT[16][68];   // asT[k][row]
    __shared__ float bs[16][68];    // bs[k][col]
    const int tid = threadIdx.x;
    const int m0 = blockIdx.y * 64;
    const int n0 = blockIdx.x * 64;
    const int ty = tid >> 4, tx = tid & 15;
    float acc[4][4] = {{0.f}};

    for (int k0 = 0; k0 < ND; k0 += 16) {
        {   // A: 64 rows x 16 k, transposed store
            int row = tid >> 2, k4 = tid & 3;
            int grow = m0 + row; if (grow > TC - 1) grow = TC - 1;
            const float4 v = *(const float4*)&ctx[(size_t)grow * ND + k0 + k4 * 4];
            asT[k4 * 4 + 0][row] = v.x; asT[k4 * 4 + 1][row] = v.y;
            asT[k4 * 4 + 2][row] = v.z; asT[k4 * 4 + 3][row] = v.w;
        }
        {   // B: 16 k x 64 cols
            int k = tid >> 4, c4 = tid & 15;
            *(float4*)&bs[k][c4 * 4] =
                *(const float4*)&Wkv[(size_t)(k0 + k) * ND + n0 + c4 * 4];
        }
        __syncthreads();
#pragma unroll
        for (int k = 0; k < 16; ++k) {
            const float4 a4 = *(const float4*)&asT[k][ty * 4];
            const float4 b4 = *(const float4*)&bs[k][tx * 4];
            const float a[4] = {a4.x, a4.y, a4.z, a4.w};
            const float b[4] = {b4.x, b4.y, b4.z, b4.w};
#pragma unroll
            for (int r = 0; r < 4; ++r)
#pragma unroll
                for (int c = 0; c < 4; ++c) acc[r][c] += a[r] * b[c];
        }
        __syncthreads();
    }
    // epilogue: bias + LN over the 64-wide row (16 lanes x 4 vals) + store
    const int h = n0 >> 6;
    const float4 g4  = *(const float4*)&gamma[tx * 4];
    const float4 be4 = *(const float4*)&beta[tx * 4];
    const float4 bk4 = *(const float4*)&bkv[n0 + tx * 4];
#pragma unroll
    for (int r = 0; r < 4; ++r) {
        int row = m0 + ty * 4 + r;
        float v0 = acc[r][0] + bk4.x, v1 = acc[r][1] + bk4.y;
        float v2 = acc[r][2] + bk4.z, v3 = acc[r][3] + bk4.w;
        float s = v0 + v1 + v2 + v3;
        s += __shfl_xor(s, 1); s += __shfl_xor(s, 2);
        s += __shfl_xor(s, 4); s += __shfl_xor(s, 8);
        float mean = s * (1.f / 64.f);
        float d0 = v0 - mean, d1 = v1 - mean, d2 = v2 - mean, d3 = v3 - mean;
        float q = d0 * d0 + d1 * d1 + d2 * d2 + d3 * d3;
        q += __shfl_xor(q, 1); q += __shfl_xor(q, 2);
        q += __shfl_xor(q, 4); q += __shfl_xor(q, 8);
        float inv = 1.f / (sqrtf(q * (1.f / 63.f)) + LN_EPS);   // ddof=1, /(std+eps)
        if (row < TC) {
            float4 o;
            o.x = g4.x * d0 * inv + be4.x;
            o.y = g4.y * d1 * inv + be4.y;
            o.z = g4.z * d2 * inv + be4.z;
            o.w = g4.w * d3 * inv + be4.w;
            *(float4*)&kvn[((size_t)h * TC + row) * DH + tx * 4] = o;
        }
    }
}

// ---------------- kernel 2: q-proj + skew scores -> sk (bf16)
// grid (cur/64, H), 256 thr. 64 tokens/block; s-chunks of 128 staged in LDS.
// Register tile 4 tokens x 8 s; LDS: qsT[i][t] + ks[i][s] (stride 130, 2-way-free reads).
__global__ __launch_bounds__(256) void skq_kernel(const float* __restrict__ x,
                                                  const float* __restrict__ Wq,
                                                  const float* __restrict__ bq,
                                                  const float* __restrict__ kvn,
                                                  unsigned short* __restrict__ sk,
                                                  int t_base, int cur) {
    __shared__ float qsT[DH][68];     // qsT[i][t]
    __shared__ float ks[DH][130];     // ks[i][s_local]; aliased as xs[t][i] in q-phase
    float (*xs)[68] = (float(*)[68])ks;
    const int tid = threadIdx.x;
    const int h = blockIdx.y;
    const int tblk = blockIdx.x * 64;

    // stage x tile: xs[t][i], 64x64
#pragma unroll
    for (int p = 0; p < 4; ++p) {
        int idx = p * 256 + tid, t = idx >> 4, c4 = idx & 15;
        *(float4*)&xs[t][c4 * 4] =
            *(const float4*)&x[(size_t)(t_base + tblk + t) * ND + h * DH + c4 * 4];
    }
    __syncthreads();
    // q[t][:] = bq + xs[t][:] @ Wq ; store transposed qsT[j][t]
#pragma unroll
    for (int p = 0; p < 4; ++p) {
        int u = p * 256 + tid, t = u >> 4, j4 = u & 15;
        float4 a = *(const float4*)&bq[j4 * 4];
        for (int i = 0; i < DH; ++i) {
            float xv = xs[t][i];
            const float4 w = *(const float4*)&Wq[i * DH + j4 * 4];
            a.x += xv * w.x; a.y += xv * w.y; a.z += xv * w.z; a.w += xv * w.w;
        }
        qsT[j4 * 4 + 0][t] = a.x; qsT[j4 * 4 + 1][t] = a.y;
        qsT[j4 * 4 + 2][t] = a.z; qsT[j4 * 4 + 3][t] = a.w;
    }
    __syncthreads();   // also guards xs -> ks reuse

    const int tg = tid >> 4;   // token group: tokens tg*4..+3
    const int sg = tid & 15;   // s group: {sg*4..+3, 64+sg*4..+3}

    for (int s0 = 0; s0 < TC; s0 += 128) {
        // stage ks[i][srow], srow 0..127 (transpose of kvn rows)
#pragma unroll
        for (int p = 0; p < 8; ++p) {
            int srow = p * 16 + (tid >> 4);
            int i4 = tid & 15;
            int s = s0 + srow;
            if (s < TC) {
                const float4 v = *(const float4*)&kvn[((size_t)h * TC + s) * DH + i4 * 4];
                ks[i4 * 4 + 0][srow] = v.x; ks[i4 * 4 + 1][srow] = v.y;
                ks[i4 * 4 + 2][srow] = v.z; ks[i4 * 4 + 3][srow] = v.w;
            }
        }
        __syncthreads();

        float acc[4][8];
#pragma unroll
        for (int r = 0; r < 4; ++r)
#pragma unroll
            for (int c = 0; c < 8; ++c) acc[r][c] = 0.f;

#pragma unroll 8
        for (int i = 0; i < DH; ++i) {
            const float4 q4 = *(const float4*)&qsT[i][tg * 4];
            const float2 ka = *(const float2*)&ks[i][sg * 4];
            const float2 kb = *(const float2*)&ks[i][sg * 4 + 2];
            const float2 kc = *(const float2*)&ks[i][64 + sg * 4];
            const float2 kd = *(const float2*)&ks[i][64 + sg * 4 + 2];
            const float qq[4] = {q4.x, q4.y, q4.z, q4.w};
            const float kk[8] = {ka.x, ka.y, kb.x, kb.y, kc.x, kc.y, kd.x, kd.y};
#pragma unroll
            for (int r = 0; r < 4; ++r)
#pragma unroll
                for (int c = 0; c < 8; ++c) acc[r][c] += qq[r] * kk[c];
        }
        __syncthreads();

        // tanh -> bf16 -> global (coalesced)
#pragma unroll
        for (int tt = 0; tt < 4; ++tt) {
            int trow = tg * 4 + tt;
            size_t base = ((size_t)h * cur + (tblk + trow)) * (size_t)TC;
            ushort4 lo;
            lo.x = f32_to_bf16(tanh_fast(acc[tt][0]));
            lo.y = f32_to_bf16(tanh_fast(acc[tt][1]));
            lo.z = f32_to_bf16(tanh_fast(acc[tt][2]));
            lo.w = f32_to_bf16(tanh_fast(acc[tt][3]));
            *(ushort4*)&sk[base + s0 + sg * 4] = lo;   // s0+sg*4+3 <= 1983 always valid
            int sup = s0 + 64 + sg * 4;
            if (sup + 3 < TC) {
                ushort4 hi;
                hi.x = f32_to_bf16(tanh_fast(acc[tt][4]));
                hi.y = f32_to_bf16(tanh_fast(acc[tt][5]));
                hi.z = f32_to_bf16(tanh_fast(acc[tt][6]));
                hi.w = f32_to_bf16(tanh_fast(acc[tt][7]));
                *(ushort4*)&sk[base + sup] = hi;
            }
        }
    }
}

// ---------------- kernel 3: rotation. 4 waves/block, wave = one (h,t).
// Uniform 63-iter loop: lane j does j row-steps (+) then 63-j col-steps (-).
__global__ __launch_bounds__(256) void rot2_kernel(const float* __restrict__ x,
                                                   const unsigned short* __restrict__ sk,
                                                   float* __restrict__ out,
                                                   int t_base, int cur) {
    __shared__ uint4 skbuf4[4][252];   // 4 x 2016 bf16
    __shared__ float xsr[4][68];
    const int lane = threadIdx.x & 63;
    const int w = threadIdx.x >> 6;
    const int u = blockIdx.x * 4 + w;
    const int tl = u >> 4;          // token within slice
    const int h = u & 15;

    {   // stage sk row (coalesced uint4)
        const uint4* src = (const uint4*)(sk + ((size_t)h * cur + tl) * (size_t)TC);
        for (int c = lane; c < 252; c += 64) skbuf4[w][c] = src[c];
    }
    const float xj = x[(size_t)(t_base + tl) * ND + h * DH + lane];
    xsr[w][lane] = xj;
    __syncthreads();

    const unsigned short* skw = (const unsigned short*)&skbuf4[w][0];
    const int j = lane;
    const int jb = (j * (j - 1)) >> 1;
    float acc = 0.f;
    int tri = 0;                       // k(k+1)/2, uniform across lanes
#pragma unroll 7
    for (int k = 0; k < 63; ++k) {
        tri += k;
        const bool cond = k < j;                      // row-mode vs col-mode
        const int idx = cond ? (jb + k) : (tri + j);  // p(j,k) : p(k+1,j)
        const float xi = xsr[w][cond ? k : (k + 1)];
        const float sv = __uint_as_float((unsigned int)skw[idx] << 16);
        acc = fmaf(sv, cond ? xi : -xi, acc);
    }
    out[(size_t)(t_base + tl) * ND + h * DH + j] = xj + EPS_ROT * acc;
}

extern "C" void kernel_launch(void* const* d_in, const int* in_sizes, int n_in,
                              void* d_out, int out_size, void* d_ws, size_t ws_size,
                              hipStream_t stream) {
    const float* x     = (const float*)d_in[0];
    const float* ctx   = (const float*)d_in[1];
    const float* Wq    = (const float*)d_in[2];
    const float* bq    = (const float*)d_in[3];
    const float* Wkv   = (const float*)d_in[4];
    const float* bkv   = (const float*)d_in[5];
    const float* gamma = (const float*)d_in[6];
    const float* beta  = (const float*)d_in[7];
    float* outp = (float*)d_out;

    float* kvn = (float*)d_ws;                               // 16*2016*64 f32 = 8.25MB
    size_t kvn_bytes = (size_t)NH * TC * DH * sizeof(float);
    size_t off = (kvn_bytes + 255) & ~(size_t)255;
    unsigned short* skbuf = (unsigned short*)((char*)d_ws + off);
    size_t avail = (ws_size > off) ? (ws_size - off) : 0;
    size_t per_tok = (size_t)NH * TC * 2;                    // 64512 B / token
    int slice = (int)((avail / per_tok) & ~(size_t)63);      // tokens per slice
    if (slice > NT) slice = NT;
    if (slice < 64) slice = 64;                              // needs ~12.5MB ws minimum

    gemm_ln<<<dim3(ND / 64, 32), 256, 0, stream>>>(ctx, Wkv, bkv, gamma, beta, kvn);

    for (int t0 = 0; t0 < NT; t0 += slice) {
        int curt = (NT - t0 < slice) ? (NT - t0) : slice;
        skq_kernel<<<dim3(curt / 64, NH), 256, 0, stream>>>(x, Wq, bq, kvn, skbuf, t0, curt);
        rot2_kernel<<<dim3(curt * 4), 256, 0, stream>>>(x, skbuf, outp, t0, curt);
    }
}

// Round 5
// 321.887 us; speedup vs baseline: 6.2462x; 1.1978x over previous
//
#include <hip/hip_runtime.h>
#include <math.h>

// PosteriorRotationLayer: B=1, T=2048, D=1024, H=16, d=64, Tc=2016
// Pipeline:
//   gemm_ln  : kvn_{hi,lo}[h][s][d] = split_bf16(LN_d64(context @ Wkv + bkv))
//   skq_mfma : sk[h][t][s] = bf16(tanh(q_t . kvn[h][s])) via 3-product split-bf16 MFMA
//   rot2     : out = x + eps * (A - A^T) x   uniform 63-iter gather per (h,t,j)
// p(j,i) = j*(j-1)/2 + i  (tril_indices(d,-1) row-major)

#define NT 2048
#define ND 1024
#define NH 16
#define DH 64
#define TC 2016
#define SPAD 2048          // padded s-rows in kvn bf16 buffers (poison tail is finite-tiny)
#define EPS_ROT 0.01f
#define LN_EPS 1e-5f

typedef __attribute__((ext_vector_type(8))) short short8;    // 8 bf16 = 4 VGPR
typedef __attribute__((ext_vector_type(16))) float f32x16;   // MFMA 32x32 acc

__device__ inline unsigned short f32_to_bf16(float f) {  // RNE
    unsigned int b = __float_as_uint(f);
    unsigned int r = (b + 0x7FFFu + ((b >> 16) & 1u)) >> 16;
    return (unsigned short)r;
}
__device__ inline float bf16_to_f32(unsigned short u) {
    return __uint_as_float((unsigned int)u << 16);
}
// clamp-free tanh: 1 - 2/(e^{2x}+1). e=inf -> 1, e=0 -> -1; no NaN for finite x.
__device__ inline float tanh_fast(float x) {
    float e = __expf(2.f * x);
    return 1.f - 2.f * __builtin_amdgcn_rcpf(e + 1.f);
}

// ---------------- kernel 1: fused GEMM + LayerNorm -> kvn hi/lo (bf16 split)
// M=2016(pad), N=1024, K=1024. 64x64 tile, 256 thr, 4x4/thread. 64-col tile == one head.
__global__ __launch_bounds__(256) void gemm_ln(const float* __restrict__ ctx,
                                               const float* __restrict__ Wkv,
                                               const float* __restrict__ bkv,
                                               const float* __restrict__ gamma,
                                               const float* __restrict__ beta,
                                               unsigned short* __restrict__ kvh,
                                               unsigned short* __restrict__ kvl) {
    __shared__ float asT[16][68];   // asT[k][row]
    __shared__ float bs[16][68];    // bs[k][col]
    const int tid = threadIdx.x;
    const int m0 = blockIdx.y * 64;
    const int n0 = blockIdx.x * 64;
    const int ty = tid >> 4, tx = tid & 15;
    float acc[4][4] = {{0.f}};

    for (int k0 = 0; k0 < ND; k0 += 16) {
        {   // A: 64 rows x 16 k, transposed store
            int row = tid >> 2, k4 = tid & 3;
            int grow = m0 + row; if (grow > TC - 1) grow = TC - 1;
            const float4 v = *(const float4*)&ctx[(size_t)grow * ND + k0 + k4 * 4];
            asT[k4 * 4 + 0][row] = v.x; asT[k4 * 4 + 1][row] = v.y;
            asT[k4 * 4 + 2][row] = v.z; asT[k4 * 4 + 3][row] = v.w;
        }
        {   // B: 16 k x 64 cols
            int k = tid >> 4, c4 = tid & 15;
            *(float4*)&bs[k][c4 * 4] =
                *(const float4*)&Wkv[(size_t)(k0 + k) * ND + n0 + c4 * 4];
        }
        __syncthreads();
#pragma unroll
        for (int k = 0; k < 16; ++k) {
            const float4 a4 = *(const float4*)&asT[k][ty * 4];
            const float4 b4 = *(const float4*)&bs[k][tx * 4];
            const float a[4] = {a4.x, a4.y, a4.z, a4.w};
            const float b[4] = {b4.x, b4.y, b4.z, b4.w};
#pragma unroll
            for (int r = 0; r < 4; ++r)
#pragma unroll
                for (int c = 0; c < 4; ++c) acc[r][c] += a[r] * b[c];
        }
        __syncthreads();
    }
    const int h = n0 >> 6;
    const float4 g4  = *(const float4*)&gamma[tx * 4];
    const float4 be4 = *(const float4*)&beta[tx * 4];
    const float4 bk4 = *(const float4*)&bkv[n0 + tx * 4];
#pragma unroll
    for (int r = 0; r < 4; ++r) {
        int row = m0 + ty * 4 + r;
        float v0 = acc[r][0] + bk4.x, v1 = acc[r][1] + bk4.y;
        float v2 = acc[r][2] + bk4.z, v3 = acc[r][3] + bk4.w;
        float s = v0 + v1 + v2 + v3;
        s += __shfl_xor(s, 1); s += __shfl_xor(s, 2);
        s += __shfl_xor(s, 4); s += __shfl_xor(s, 8);
        float mean = s * (1.f / 64.f);
        float d0 = v0 - mean, d1 = v1 - mean, d2 = v2 - mean, d3 = v3 - mean;
        float q = d0 * d0 + d1 * d1 + d2 * d2 + d3 * d3;
        q += __shfl_xor(q, 1); q += __shfl_xor(q, 2);
        q += __shfl_xor(q, 4); q += __shfl_xor(q, 8);
        float inv = 1.f / (sqrtf(q * (1.f / 63.f)) + LN_EPS);   // ddof=1, /(std+eps)
        if (row < TC) {
            float o0 = g4.x * d0 * inv + be4.x;
            float o1 = g4.y * d1 * inv + be4.y;
            float o2 = g4.z * d2 * inv + be4.z;
            float o3 = g4.w * d3 * inv + be4.w;
            ushort4 hv, lv;
            hv.x = f32_to_bf16(o0); lv.x = f32_to_bf16(o0 - bf16_to_f32(hv.x));
            hv.y = f32_to_bf16(o1); lv.y = f32_to_bf16(o1 - bf16_to_f32(hv.y));
            hv.z = f32_to_bf16(o2); lv.z = f32_to_bf16(o2 - bf16_to_f32(hv.z));
            hv.w = f32_to_bf16(o3); lv.w = f32_to_bf16(o3 - bf16_to_f32(hv.w));
            size_t base = ((size_t)h * SPAD + row) * DH + tx * 4;
            *(ushort4*)&kvh[base] = hv;
            *(ushort4*)&kvl[base] = lv;
        }
    }
}

// ---------------- kernel 2: q-proj + split-bf16 MFMA scores -> sk (bf16)
// grid (cur/64, 2 s-halves, H), 256 thr = 4 waves in 2x2 (32t x 32s quadrants).
// Inner s-loop: barrier-free; B-frags straight from global (k-contiguous 16B/lane).
__global__ __launch_bounds__(256) void skq_mfma(const float* __restrict__ x,
                                                const float* __restrict__ Wq,
                                                const float* __restrict__ bq,
                                                const unsigned short* __restrict__ kvh,
                                                const unsigned short* __restrict__ kvl,
                                                unsigned short* __restrict__ sk,
                                                int t_base, int cur) {
    __shared__ float xs[64][68];
    __shared__ unsigned short qh[64][72];   // pad 72: frag b128 reads 4-way max
    __shared__ unsigned short ql[64][72];
    const int tid = threadIdx.x;
    const int h = blockIdx.z;
    const int sHalf = blockIdx.y;
    const int tblk = blockIdx.x * 64;

    // stage x tile 64x64
#pragma unroll
    for (int p = 0; p < 4; ++p) {
        int idx = p * 256 + tid, t = idx >> 4, c4 = idx & 15;
        *(float4*)&xs[t][c4 * 4] =
            *(const float4*)&x[(size_t)(t_base + tblk + t) * ND + h * DH + c4 * 4];
    }
    __syncthreads();
    // q = xs @ Wq + bq, split to bf16 hi/lo in LDS
#pragma unroll
    for (int p = 0; p < 4; ++p) {
        int u = p * 256 + tid, t = u >> 4, j4 = u & 15;
        float4 a = *(const float4*)&bq[j4 * 4];
        for (int i = 0; i < DH; ++i) {
            float xv = xs[t][i];
            const float4 w = *(const float4*)&Wq[i * DH + j4 * 4];
            a.x += xv * w.x; a.y += xv * w.y; a.z += xv * w.z; a.w += xv * w.w;
        }
        ushort4 hv, lv;
        hv.x = f32_to_bf16(a.x); lv.x = f32_to_bf16(a.x - bf16_to_f32(hv.x));
        hv.y = f32_to_bf16(a.y); lv.y = f32_to_bf16(a.y - bf16_to_f32(hv.y));
        hv.z = f32_to_bf16(a.z); lv.z = f32_to_bf16(a.z - bf16_to_f32(hv.z));
        hv.w = f32_to_bf16(a.w); lv.w = f32_to_bf16(a.w - bf16_to_f32(hv.w));
        *(ushort4*)&qh[t][j4 * 4] = hv;
        *(ushort4*)&ql[t][j4 * 4] = lv;
    }
    __syncthreads();

    const int lane = tid & 63;
    const int wid = tid >> 6;
    const int wr = wid >> 1, wc = wid & 1;   // 2x2 wave quadrants
    const int lrow = lane & 31;
    const int khalf = lane >> 5;             // k-offset 0/8 within K=16 step

    // A-frags once per block: q rows wr*32+lrow, k = ks*16 + khalf*8 + [0..7]
    short8 Ah[4], Al[4];
    {
        const int t = wr * 32 + lrow;
#pragma unroll
        for (int ks = 0; ks < 4; ++ks) {
            Ah[ks] = *(const short8*)&qh[t][ks * 16 + khalf * 8];
            Al[ks] = *(const short8*)&ql[t][ks * 16 + khalf * 8];
        }
    }

    const int scol0 = sHalf * 1024 + wc * 32 + lrow;     // this lane's B column (s)
    const unsigned short* bh = kvh + ((size_t)h * SPAD + scol0) * DH + khalf * 8;
    const unsigned short* bl = kvl + ((size_t)h * SPAD + scol0) * DH + khalf * 8;

    for (int st = 0; st < 16; ++st) {
        short8 Bh[4], Bl[4];
        const size_t soff = (size_t)st * 64 * DH;        // 64 s-rows per step
#pragma unroll
        for (int ks = 0; ks < 4; ++ks) {
            Bh[ks] = *(const short8*)&bh[soff + ks * 16];
            Bl[ks] = *(const short8*)&bl[soff + ks * 16];
        }
        f32x16 acc = (f32x16)(0.0f);
#pragma unroll
        for (int ks = 0; ks < 4; ++ks) {
            acc = __builtin_amdgcn_mfma_f32_32x32x16_bf16(Ah[ks], Bh[ks], acc, 0, 0, 0);
            acc = __builtin_amdgcn_mfma_f32_32x32x16_bf16(Ah[ks], Bl[ks], acc, 0, 0, 0);
            acc = __builtin_amdgcn_mfma_f32_32x32x16_bf16(Al[ks], Bh[ks], acc, 0, 0, 0);
        }
        const int sq = sHalf * 1024 + st * 64 + wc * 32;   // quadrant col base
        if (sq < TC) {                                      // wave-uniform tail guard
            const int s = sq + lrow;                        // C col = lane&31
            const size_t outb = ((size_t)h * cur + (tblk + wr * 32)) * (size_t)TC;
#pragma unroll
            for (int r = 0; r < 16; ++r) {
                const int row = (r & 3) + 8 * (r >> 2) + 4 * khalf;   // C/D layout (m74/m101)
                sk[outb + (size_t)row * TC + s] = f32_to_bf16(tanh_fast(acc[r]));
            }
        }
    }
}

// ---------------- kernel 3: rotation. 4 waves/block, wave = one (h,t).
// Uniform 63-iter loop: lane j does j row-steps (+) then 63-j col-steps (-).
__global__ __launch_bounds__(256) void rot2_kernel(const float* __restrict__ x,
                                                   const unsigned short* __restrict__ sk,
                                                   float* __restrict__ out,
                                                   int t_base, int cur) {
    __shared__ uint4 skbuf4[4][252];   // 4 x 2016 bf16
    __shared__ float xsr[4][68];
    const int lane = threadIdx.x & 63;
    const int w = threadIdx.x >> 6;
    const int u = blockIdx.x * 4 + w;
    const int tl = u >> 4;          // token within slice
    const int h = u & 15;

    {   // stage sk row (coalesced uint4)
        const uint4* src = (const uint4*)(sk + ((size_t)h * cur + tl) * (size_t)TC);
        for (int c = lane; c < 252; c += 64) skbuf4[w][c] = src[c];
    }
    const float xj = x[(size_t)(t_base + tl) * ND + h * DH + lane];
    xsr[w][lane] = xj;
    __syncthreads();

    const unsigned short* skw = (const unsigned short*)&skbuf4[w][0];
    const int j = lane;
    const int jb = (j * (j - 1)) >> 1;
    float acc = 0.f;
    int tri = 0;                       // k(k+1)/2, uniform across lanes
#pragma unroll 7
    for (int k = 0; k < 63; ++k) {
        tri += k;
        const bool cond = k < j;                      // row-mode vs col-mode
        const int idx = cond ? (jb + k) : (tri + j);  // p(j,k) : p(k+1,j)
        const float xi = xsr[w][cond ? k : (k + 1)];
        const float sv = __uint_as_float((unsigned int)skw[idx] << 16);
        acc = fmaf(sv, cond ? xi : -xi, acc);
    }
    out[(size_t)(t_base + tl) * ND + h * DH + j] = xj + EPS_ROT * acc;
}

extern "C" void kernel_launch(void* const* d_in, const int* in_sizes, int n_in,
                              void* d_out, int out_size, void* d_ws, size_t ws_size,
                              hipStream_t stream) {
    const float* x     = (const float*)d_in[0];
    const float* ctx   = (const float*)d_in[1];
    const float* Wq    = (const float*)d_in[2];
    const float* bq    = (const float*)d_in[3];
    const float* Wkv   = (const float*)d_in[4];
    const float* bkv   = (const float*)d_in[5];
    const float* gamma = (const float*)d_in[6];
    const float* beta  = (const float*)d_in[7];
    float* outp = (float*)d_out;

    unsigned short* kvh = (unsigned short*)d_ws;              // 16*2048*64 bf16 = 4.19MB
    unsigned short* kvl = kvh + (size_t)NH * SPAD * DH;       // same
    size_t kv_bytes = (size_t)NH * SPAD * DH * 2 * sizeof(unsigned short);
    size_t off = (kv_bytes + 255) & ~(size_t)255;
    unsigned short* skbuf = (unsigned short*)((char*)d_ws + off);
    size_t avail = (ws_size > off) ? (ws_size - off) : 0;
    size_t per_tok = (size_t)NH * TC * 2;                     // 64512 B / token
    int slice = (int)((avail / per_tok) & ~(size_t)63);       // tokens per slice
    if (slice > NT) slice = NT;
    if (slice < 64) slice = 64;                               // needs ~12.5MB ws minimum

    gemm_ln<<<dim3(ND / 64, 32), 256, 0, stream>>>(ctx, Wkv, bkv, gamma, beta, kvh, kvl);

    for (int t0 = 0; t0 < NT; t0 += slice) {
        int curt = (NT - t0 < slice) ? (NT - t0) : slice;
        skq_mfma<<<dim3(curt / 64, 2, NH), 256, 0, stream>>>(x, Wq, bq, kvh, kvl, skbuf, t0, curt);
        rot2_kernel<<<dim3(curt * 4), 256, 0, stream>>>(x, skbuf, outp, t0, curt);
    }
}